// Round 1
// baseline (1489.731 us; speedup 1.0000x reference)
//
#include <hip/hip_runtime.h>
#include <cstdint>
#include <cstddef>

#define N_NODES 12288
#define B_EX    64
#define R_REG   36
#define E_EDGES 196608
#define DD_IN   512
#define DD_OUT  512
#define P_DIM   256
#define D_IMG   1024

// ---------------- generic tiled fp32 GEMM: C = [C +] A@B + bias, optional relu ----
// A: [M,K] row-major, B: [K,N] row-major, C: [M,N]. M%64==0, N%64==0, K%16==0.
template<bool HAS_BIAS, bool ADD_C, bool RELU>
__global__ __launch_bounds__(256) void gemm_f32(
    const float* __restrict__ A, const float* __restrict__ Bm,
    const float* __restrict__ bias, float* __restrict__ C,
    int M, int Nn, int K)
{
    __shared__ float As[16][68];
    __shared__ float Bs[16][68];
    const int tid = threadIdx.x;
    const int tx = tid & 15;        // 0..15 -> 4 cols each
    const int ty = tid >> 4;        // 0..15 -> 4 rows each
    const int row0 = blockIdx.y * 64;
    const int col0 = blockIdx.x * 64;

    const int arow = tid >> 2;          // 0..63
    const int ac4  = (tid & 3) * 4;     // 0,4,8,12
    const int brow = tid >> 4;          // 0..15
    const int bc4  = (tid & 15) * 4;    // 0..60

    float acc[4][4] = {};

    for (int k0 = 0; k0 < K; k0 += 16) {
        float4 av = *(const float4*)&A[(size_t)(row0 + arow) * K + k0 + ac4];
        float4 bv = *(const float4*)&Bm[(size_t)(k0 + brow) * Nn + col0 + bc4];
        As[ac4 + 0][arow] = av.x;
        As[ac4 + 1][arow] = av.y;
        As[ac4 + 2][arow] = av.z;
        As[ac4 + 3][arow] = av.w;
        *(float4*)&Bs[brow][bc4] = bv;
        __syncthreads();
#pragma unroll
        for (int k = 0; k < 16; ++k) {
            float4 a4 = *(const float4*)&As[k][ty * 4];
            float4 b4 = *(const float4*)&Bs[k][tx * 4];
            acc[0][0] += a4.x * b4.x; acc[0][1] += a4.x * b4.y; acc[0][2] += a4.x * b4.z; acc[0][3] += a4.x * b4.w;
            acc[1][0] += a4.y * b4.x; acc[1][1] += a4.y * b4.y; acc[1][2] += a4.y * b4.z; acc[1][3] += a4.y * b4.w;
            acc[2][0] += a4.z * b4.x; acc[2][1] += a4.z * b4.y; acc[2][2] += a4.z * b4.z; acc[2][3] += a4.z * b4.w;
            acc[3][0] += a4.w * b4.x; acc[3][1] += a4.w * b4.y; acc[3][2] += a4.w * b4.z; acc[3][3] += a4.w * b4.w;
        }
        __syncthreads();
    }

#pragma unroll
    for (int i = 0; i < 4; ++i) {
        int row = row0 + ty * 4 + i;
#pragma unroll
        for (int j = 0; j < 4; ++j) {
            int col = col0 + tx * 4 + j;
            float v = acc[i][j];
            if (HAS_BIAS) v += bias[col];
            size_t idx = (size_t)row * Nn + col;
            if (ADD_C) v += C[idx];
            if (RELU) v = fmaxf(v, 0.f);
            C[idx] = v;
        }
    }
}

// ---------------- attention logits + softmax over 36 regions: one wave per node ----
__global__ __launch_bounds__(256) void att_kernel(
    const float* __restrict__ node_proj, const float* __restrict__ img_proj,
    const int* __restrict__ batch_ids, const float* __restrict__ Wa,
    float* __restrict__ att)
{
    const int n = blockIdx.x * 4 + (threadIdx.x >> 6);
    const int lane = threadIdx.x & 63;
    const int b = batch_ids[n];
    const int r = (lane < R_REG) ? lane : 0;
    const float* np = node_proj + (size_t)n * P_DIM;
    const float* ip = img_proj + ((size_t)b * R_REG + r) * P_DIM;

    float logit = 0.f;
    for (int c = 0; c < P_DIM; ++c) {
        logit += tanhf(np[c] + ip[c]) * Wa[c];
    }
    // ba is a constant shift of all logits -> cancels in the softmax; skipped.
    if (lane >= R_REG) logit = -INFINITY;

    float m = logit;
#pragma unroll
    for (int off = 32; off; off >>= 1) m = fmaxf(m, __shfl_xor(m, off));
    float e = (lane < R_REG) ? __expf(logit - m) : 0.f;
    float s = e;
#pragma unroll
    for (int off = 32; off; off >>= 1) s += __shfl_xor(s, off);
    if (lane < R_REG) att[(size_t)n * R_REG + lane] = e / s;
}

// ---------------- attended image feature: img[n] = sum_r att[n][r] * img_feats[b][r] ----
__global__ __launch_bounds__(256) void img_att_kernel(
    const float* __restrict__ att, const float* __restrict__ img_feats,
    const int* __restrict__ batch_ids, float* __restrict__ img)
{
    const int n = blockIdx.x;
    const int t = threadIdx.x;
    __shared__ float a_s[R_REG];
    if (t < R_REG) a_s[t] = att[(size_t)n * R_REG + t];
    __syncthreads();
    const int b = batch_ids[n];
    const float* imf = img_feats + (size_t)b * R_REG * D_IMG;
    float acc0 = 0.f, acc1 = 0.f, acc2 = 0.f, acc3 = 0.f;
    for (int r = 0; r < R_REG; ++r) {
        float a = a_s[r];
        acc0 += a * imf[r * D_IMG + t];
        acc1 += a * imf[r * D_IMG + t + 256];
        acc2 += a * imf[r * D_IMG + t + 512];
        acc3 += a * imf[r * D_IMG + t + 768];
    }
    float* o = img + (size_t)n * D_IMG;
    o[t] = acc0; o[t + 256] = acc1; o[t + 512] = acc2; o[t + 768] = acc3;
}

// ---------------- edge scatter: neigh[dst] += h1[src], atomics ----
__global__ __launch_bounds__(256) void edge_kernel(
    const int* __restrict__ src, const int* __restrict__ dst,
    const float* __restrict__ h1, float* __restrict__ neigh)
{
    const int e = blockIdx.x;
    const int t = threadIdx.x;
    const int s = src[e], d = dst[e];
    const float* hs = h1 + (size_t)s * DD_OUT;
    float* nd = neigh + (size_t)d * DD_OUT;
    atomicAdd(&nd[t], hs[t]);
    atomicAdd(&nd[t + 256], hs[t + 256]);
}

extern "C" void kernel_launch(void* const* d_in, const int* in_sizes, int n_in,
                              void* d_out, int out_size, void* d_ws, size_t ws_size,
                              hipStream_t stream) {
    const float* h         = (const float*)d_in[0];
    const float* img_feats = (const float*)d_in[1];
    const int*   batch_ids = (const int*)d_in[2];
    const int*   src       = (const int*)d_in[3];
    const int*   dst       = (const int*)d_in[4];
    const float* Wf  = (const float*)d_in[5];
    const float* bf  = (const float*)d_in[6];
    const float* Wi  = (const float*)d_in[7];
    const float* bi  = (const float*)d_in[8];
    const float* Wa  = (const float*)d_in[9];
    // d_in[10] = ba: constant logit shift, cancels in softmax
    const float* Wn  = (const float*)d_in[11];
    const float* bn  = (const float*)d_in[12];
    const float* Wim = (const float*)d_in[13];
    const float* bim = (const float*)d_in[14];
    const float* Wap = (const float*)d_in[15];
    const float* bap = (const float*)d_in[16];
    float* out = (float*)d_out;
    float* ws  = (float*)d_ws;

    // workspace layout (floats)
    float* h1    = ws;                               // 12288*512   = 6291456
    float* neigh = h1 + (size_t)N_NODES * DD_OUT;    // 12288*512   = 6291456
    float* att   = neigh + (size_t)N_NODES * DD_OUT; // 12288*36    = 442368
    float* pool  = att + (size_t)N_NODES * R_REG;
    float* node_proj = pool;                               // 12288*256 = 3145728
    float* img_proj  = pool + (size_t)N_NODES * P_DIM;     // 2304*256  = 589824
    float* img       = pool;  // overlays node_proj/img_proj once att is computed
    // total: 13025280 + 12582912 floats = ~102.4 MB

    dim3 blk(256);

    // 1. node_proj = h @ Wf + bf   [12288,256], K=512
    gemm_f32<true, false, false><<<dim3(P_DIM / 64, N_NODES / 64), blk, 0, stream>>>(
        h, Wf, bf, node_proj, N_NODES, P_DIM, DD_IN);

    // 2. img_proj = img_feats @ Wi + bi   [2304,256], K=1024
    gemm_f32<true, false, false><<<dim3(P_DIM / 64, (B_EX * R_REG) / 64), blk, 0, stream>>>(
        img_feats, Wi, bi, img_proj, B_EX * R_REG, P_DIM, D_IMG);

    // 3. attention weights [12288,36]
    att_kernel<<<dim3(N_NODES / 4), blk, 0, stream>>>(node_proj, img_proj, batch_ids, Wa, att);

    // 4. img = weighted sum of regions [12288,1024]  (overlays node_proj/img_proj)
    img_att_kernel<<<dim3(N_NODES), blk, 0, stream>>>(att, img_feats, batch_ids, img);

    // 5. h1 = h @ Wn + bn  [12288,512], K=512
    gemm_f32<true, false, false><<<dim3(DD_OUT / 64, N_NODES / 64), blk, 0, stream>>>(
        h, Wn, bn, h1, N_NODES, DD_OUT, DD_IN);

    // 6. neigh = segment_sum(h1[src], dst)
    hipMemsetAsync(neigh, 0, (size_t)N_NODES * DD_OUT * sizeof(float), stream);
    edge_kernel<<<dim3(E_EDGES), blk, 0, stream>>>(src, dst, h1, neigh);

    // 7. msg = neigh + img @ Wim + bim   (in-place into neigh)
    gemm_f32<true, true, false><<<dim3(DD_OUT / 64, N_NODES / 64), blk, 0, stream>>>(
        img, Wim, bim, neigh, N_NODES, DD_OUT, D_IMG);

    // 8. out = msg @ Wap[:512] + bap
    gemm_f32<true, false, false><<<dim3(DD_OUT / 64, N_NODES / 64), blk, 0, stream>>>(
        neigh, Wap, bap, out, N_NODES, DD_OUT, DD_OUT);

    // 9. out = relu(out + h1 @ Wap[512:])
    gemm_f32<false, true, true><<<dim3(DD_OUT / 64, N_NODES / 64), blk, 0, stream>>>(
        h1, Wap + (size_t)DD_OUT * DD_OUT, nullptr, out, N_NODES, DD_OUT, DD_OUT);
}

// Round 2
// 434.824 us; speedup vs baseline: 3.4261x; 3.4261x over previous
//
#include <hip/hip_runtime.h>
#include <cstdint>
#include <cstddef>

#define N_NODES 12288
#define B_EX    64
#define R_REG   36
#define E_EDGES 196608
#define DD_IN   512
#define DD_OUT  512
#define P_DIM   256
#define D_IMG   1024

typedef unsigned short ushort;
typedef __bf16 bf16x8 __attribute__((ext_vector_type(8)));
typedef float f32x4 __attribute__((ext_vector_type(4)));
typedef ushort ushort4v __attribute__((ext_vector_type(4)));
typedef ushort ushort8v __attribute__((ext_vector_type(8)));

__device__ __forceinline__ ushort f2bf(float f) {
    uint32_t u = __float_as_uint(f);
    uint32_t r = (u + 0x7fffu + ((u >> 16) & 1u)) >> 16;
    return (ushort)r;
}
__device__ __forceinline__ float bf2f(ushort u) {
    return __uint_as_float(((uint32_t)u) << 16);
}
__device__ __forceinline__ void gload_lds16(const void* g, void* l) {
    __builtin_amdgcn_global_load_lds((const __attribute__((address_space(1))) void*)g,
                                     (__attribute__((address_space(3))) void*)l, 16, 0, 0);
}
__device__ __forceinline__ float fast_tanh(float x) {
    float t = __expf(2.f * x);
    return 1.f - __fdividef(2.f, t + 1.f);
}

// ================= bf16 MFMA GEMM: C = [Cadd +] A @ BT^T + bias =================
// A: [M][K] bf16 row-major. BT: [N][K] bf16 (i.e. B transposed). M%128==0, N%128==0, K%64==0.
// Outputs: optional fp32 C [M][Nn], optional bf16 C at Cb[row*ldb + col + coloff].
template<bool HAS_BIAS, bool ADD_C, bool RELU, bool OUT_F32, bool OUT_BF16>
__global__ __launch_bounds__(256) void gemm_bf16mfma(
    const ushort* __restrict__ A, const ushort* __restrict__ BT,
    const float* __restrict__ bias, const float* __restrict__ Cadd,
    float* __restrict__ Cf, ushort* __restrict__ Cb,
    int M, int Nn, int K, int ldb, int coloff)
{
    __shared__ ushort As[128 * 64];
    __shared__ ushort Bs[128 * 64];
    const int tid = threadIdx.x;
    const int lane = tid & 63;
    const int wid = tid >> 6;
    const int wm = wid >> 1, wn = wid & 1;
    const int m0 = blockIdx.y * 128, n0 = blockIdx.x * 128;

    f32x4 acc[4][4] = {};

    const int srow = tid >> 3;   // 0..31 (row within 32-row staging group)
    const int schk = tid & 7;    // 16B chunk within 64-elem row
    const char* AsB = (const char*)As;
    const char* BsB = (const char*)Bs;

    for (int k0 = 0; k0 < K; k0 += 64) {
        // ---- stage 128x64 A-tile and B-tile, XOR-swizzled source, linear LDS dest ----
#pragma unroll
        for (int i = 0; i < 4; ++i) {
            int row = i * 32 + srow;
            int ca = (schk ^ (row & 7)) * 8;
            gload_lds16(A + (size_t)(m0 + row) * K + k0 + ca,
                        (char*)As + i * 4096 + wid * 1024);
            int cb = (schk ^ (row & 7)) * 8;
            gload_lds16(BT + (size_t)(n0 + row) * K + k0 + cb,
                        (char*)Bs + i * 4096 + wid * 1024);
        }
        __syncthreads();
#pragma unroll
        for (int kk = 0; kk < 2; ++kk) {
            const int kc = kk * 4 + (lane >> 4);  // 16B chunk index along K
            bf16x8 af[4], bfr[4];
#pragma unroll
            for (int i = 0; i < 4; ++i) {
                int row = wm * 64 + i * 16 + (lane & 15);
                af[i] = *(const bf16x8*)(AsB + row * 128 + ((kc ^ (row & 7)) << 4));
            }
#pragma unroll
            for (int j = 0; j < 4; ++j) {
                int col = wn * 64 + j * 16 + (lane & 15);
                bfr[j] = *(const bf16x8*)(BsB + col * 128 + ((kc ^ (col & 7)) << 4));
            }
#pragma unroll
            for (int i = 0; i < 4; ++i)
#pragma unroll
                for (int j = 0; j < 4; ++j)
                    acc[i][j] = __builtin_amdgcn_mfma_f32_16x16x32_bf16(af[i], bfr[j], acc[i][j], 0, 0, 0);
        }
        __syncthreads();
    }

#pragma unroll
    for (int i = 0; i < 4; ++i) {
#pragma unroll
        for (int j = 0; j < 4; ++j) {
#pragma unroll
            for (int q = 0; q < 4; ++q) {
                int row = m0 + wm * 64 + i * 16 + (lane >> 4) * 4 + q;
                int col = n0 + wn * 64 + j * 16 + (lane & 15);
                float v = acc[i][j][q];
                if (HAS_BIAS) v += bias[col];
                if (ADD_C)    v += Cadd[(size_t)row * Nn + col];
                if (RELU)     v = fmaxf(v, 0.f);
                if (OUT_F32)  Cf[(size_t)row * Nn + col] = v;
                if (OUT_BF16) Cb[(size_t)row * ldb + col + coloff] = f2bf(v);
            }
        }
    }
}

// ================= fp32 -> bf16 convert =================
__global__ __launch_bounds__(256) void cvt_f32_bf16(
    const float* __restrict__ in, ushort* __restrict__ out, int n4)
{
    int i = blockIdx.x * 256 + threadIdx.x;
    if (i >= n4) return;
    float4 v = ((const float4*)in)[i];
    ushort4v o;
    o[0] = f2bf(v.x); o[1] = f2bf(v.y); o[2] = f2bf(v.z); o[3] = f2bf(v.w);
    ((ushort4v*)out)[i] = o;
}

// ================= W [K][N] fp32 -> WT [N][K] bf16 =================
__global__ __launch_bounds__(256) void transpose_cvt(
    const float* __restrict__ W, ushort* __restrict__ WT, int K, int N)
{
    __shared__ float t[64][65];
    const int n0 = blockIdx.x * 64, k0 = blockIdx.y * 64;
    const int tx = threadIdx.x & 15, ty = threadIdx.x >> 4;
#pragma unroll
    for (int r = 0; r < 4; ++r) {
        float4 v = *(const float4*)&W[(size_t)(k0 + ty * 4 + r) * N + n0 + tx * 4];
        t[ty * 4 + r][tx * 4 + 0] = v.x;
        t[ty * 4 + r][tx * 4 + 1] = v.y;
        t[ty * 4 + r][tx * 4 + 2] = v.z;
        t[ty * 4 + r][tx * 4 + 3] = v.w;
    }
    __syncthreads();
    const int nl = threadIdx.x >> 2, kq = (threadIdx.x & 3) * 16;
    ushort u[16] __attribute__((aligned(16)));
#pragma unroll
    for (int c = 0; c < 16; ++c) u[c] = f2bf(t[kq + c][nl]);
    ushort* d = &WT[(size_t)(n0 + nl) * K + k0 + kq];
    *(ushort8v*)d = *(ushort8v*)&u[0];
    *(ushort8v*)(d + 8) = *(ushort8v*)&u[8];
}

// ================= attention logits + softmax (fast tanh, 1 wave/node) =================
__global__ __launch_bounds__(256) void att_kernel(
    const float* __restrict__ node_proj, const float* __restrict__ img_proj,
    const int* __restrict__ batch_ids, const float* __restrict__ Wa,
    float* __restrict__ att)
{
    const int n = blockIdx.x * 4 + (threadIdx.x >> 6);
    const int lane = threadIdx.x & 63;
    const int b = batch_ids[n];
    const int r = (lane < R_REG) ? lane : 0;
    const float4* np4 = (const float4*)(node_proj + (size_t)n * P_DIM);
    const float4* ip4 = (const float4*)(img_proj + ((size_t)b * R_REG + r) * P_DIM);
    const float4* wa4 = (const float4*)Wa;

    float a0 = 0.f, a1 = 0.f, a2 = 0.f, a3 = 0.f;
#pragma unroll 4
    for (int c = 0; c < P_DIM / 4; ++c) {
        float4 x = np4[c], y = ip4[c], w = wa4[c];
        a0 += fast_tanh(x.x + y.x) * w.x;
        a1 += fast_tanh(x.y + y.y) * w.y;
        a2 += fast_tanh(x.z + y.z) * w.z;
        a3 += fast_tanh(x.w + y.w) * w.w;
    }
    float logit = (a0 + a1) + (a2 + a3);
    if (lane >= R_REG) logit = -INFINITY;

    float m = logit;
#pragma unroll
    for (int off = 32; off; off >>= 1) m = fmaxf(m, __shfl_xor(m, off));
    float e = (lane < R_REG) ? __expf(logit - m) : 0.f;
    float s = e;
#pragma unroll
    for (int off = 32; off; off >>= 1) s += __shfl_xor(s, off);
    if (lane < R_REG) att[(size_t)n * R_REG + lane] = e / s;
}

// ================= attended image feature -> bf16 [N][1024] =================
__global__ __launch_bounds__(256) void img_att_kernel(
    const float* __restrict__ att, const float* __restrict__ img_feats,
    const int* __restrict__ batch_ids, ushort* __restrict__ img_bf)
{
    const int n = blockIdx.x;
    const int t = threadIdx.x;
    __shared__ float a_s[R_REG];
    if (t < R_REG) a_s[t] = att[(size_t)n * R_REG + t];
    __syncthreads();
    const int b = batch_ids[n];
    const float* imf = img_feats + (size_t)b * R_REG * D_IMG;
    float acc0 = 0.f, acc1 = 0.f, acc2 = 0.f, acc3 = 0.f;
    for (int r = 0; r < R_REG; ++r) {
        float a = a_s[r];
        acc0 += a * imf[r * D_IMG + t];
        acc1 += a * imf[r * D_IMG + t + 256];
        acc2 += a * imf[r * D_IMG + t + 512];
        acc3 += a * imf[r * D_IMG + t + 768];
    }
    ushort* o = img_bf + (size_t)n * D_IMG;
    o[t] = f2bf(acc0); o[t + 256] = f2bf(acc1);
    o[t + 512] = f2bf(acc2); o[t + 768] = f2bf(acc3);
}

// ================= CSR build (counting sort by dst) + gather =================
__global__ __launch_bounds__(256) void count_deg(const int* __restrict__ dst, int* __restrict__ deg) {
    int i = blockIdx.x * 256 + threadIdx.x;
    if (i < E_EDGES) atomicAdd(&deg[dst[i]], 1);
}

__global__ __launch_bounds__(256) void scan_deg(const int* __restrict__ deg, int* __restrict__ off) {
    __shared__ int s[257];
    const int t = threadIdx.x;
    const int base = t * 48;   // 256*48 = 12288
    int sum = 0;
    for (int j = 0; j < 48; ++j) sum += deg[base + j];
    s[t] = sum;
    __syncthreads();
    if (t == 0) {
        int acc = 0;
        for (int i = 0; i < 256; ++i) { int v = s[i]; s[i] = acc; acc += v; }
        s[256] = acc;
    }
    __syncthreads();
    int run = s[t];
    for (int j = 0; j < 48; ++j) { off[base + j] = run; run += deg[base + j]; }
    if (t == 255) off[N_NODES] = s[256];
}

__global__ __launch_bounds__(256) void scatter_edges(
    const int* __restrict__ src, const int* __restrict__ dst,
    const int* __restrict__ off, int* __restrict__ cur, int* __restrict__ ssrc)
{
    int i = blockIdx.x * 256 + threadIdx.x;
    if (i < E_EDGES) {
        int d = dst[i];
        int p = off[d] + atomicAdd(&cur[d], 1);
        ssrc[p] = src[i];
    }
}

__global__ __launch_bounds__(256) void gather_neigh(
    const int* __restrict__ off, const int* __restrict__ ssrc,
    const ushort* __restrict__ h1b /* cat+512, ld 1024 */, float* __restrict__ neigh)
{
    const int n = blockIdx.x, t = threadIdx.x;
    const int e0 = off[n], e1 = off[n + 1];
    float a0 = 0.f, a1 = 0.f;
    for (int e = e0; e < e1; ++e) {
        const ushort* row = h1b + (size_t)ssrc[e] * 1024;
        a0 += bf2f(row[t]);
        a1 += bf2f(row[t + 256]);
    }
    neigh[(size_t)n * DD_OUT + t] = a0;
    neigh[(size_t)n * DD_OUT + t + 256] = a1;
}

extern "C" void kernel_launch(void* const* d_in, const int* in_sizes, int n_in,
                              void* d_out, int out_size, void* d_ws, size_t ws_size,
                              hipStream_t stream) {
    const float* h         = (const float*)d_in[0];
    const float* img_feats = (const float*)d_in[1];
    const int*   batch_ids = (const int*)d_in[2];
    const int*   src       = (const int*)d_in[3];
    const int*   dst       = (const int*)d_in[4];
    const float* Wf  = (const float*)d_in[5];
    const float* bf  = (const float*)d_in[6];
    const float* Wi  = (const float*)d_in[7];
    const float* bi  = (const float*)d_in[8];
    const float* Wa  = (const float*)d_in[9];
    // d_in[10] = ba: constant logit shift, cancels in softmax
    const float* Wn  = (const float*)d_in[11];
    const float* bn  = (const float*)d_in[12];
    const float* Wim = (const float*)d_in[13];
    const float* bim = (const float*)d_in[14];
    const float* Wap = (const float*)d_in[15];
    const float* bap = (const float*)d_in[16];
    float* out = (float*)d_out;
    float* ws  = (float*)d_ws;

    // ---- workspace layout (offsets in 4-byte units) ----
    ushort* h_bf    = (ushort*)(ws + 0);         // [12288][512] bf16  (dead after h1 GEMM)
    ushort* img_bf  = (ushort*)(ws + 3145728);   // [12288][1024] bf16 (dead after msg GEMM)
    // R3: node_proj/img_proj/imgf_bf/att all dead before neigh is written over them
    float*  node_proj = ws + 9437184;            // [12288][256] f32
    float*  img_proj  = ws + 12582912;           // [2304][256]  f32
    ushort* imgf_bf   = (ushort*)(ws + 13172736);// [2304][1024] bf16
    float*  att       = ws + 14352384;           // [12288][36]  f32
    float*  neigh     = ws + 9437184;            // [12288][512] f32 (overlays R3)
    ushort* cat       = (ushort*)(ws + 15728640);// [12288][1024] bf16: cols 0-511 msg, 512-1023 h1
    ushort* WfT  = (ushort*)(ws + 22020096);     // [256][512]
    ushort* WiT  = (ushort*)(ws + 22085632);     // [256][1024]
    ushort* WnT  = (ushort*)(ws + 22216704);     // [512][512]
    ushort* WimT = (ushort*)(ws + 22347776);     // [512][1024]
    ushort* WapT = (ushort*)(ws + 22609920);     // [512][1024]
    int* deg  = (int*)(ws + 22872064);           // [12288]
    int* cur  = deg + N_NODES;                   // [12288]
    int* offs = cur + N_NODES;                   // [12289]
    int* ssrc = offs + N_NODES + 1;              // [196608]

    dim3 blk(256);

    // ---- converts & weight transposes ----
    cvt_f32_bf16<<<dim3((N_NODES * DD_IN / 4 + 255) / 256), blk, 0, stream>>>(h, h_bf, N_NODES * DD_IN / 4);
    cvt_f32_bf16<<<dim3((B_EX * R_REG * D_IMG / 4 + 255) / 256), blk, 0, stream>>>(img_feats, imgf_bf, B_EX * R_REG * D_IMG / 4);
    transpose_cvt<<<dim3(P_DIM / 64, DD_IN / 64), blk, 0, stream>>>(Wf, WfT, DD_IN, P_DIM);
    transpose_cvt<<<dim3(P_DIM / 64, D_IMG / 64), blk, 0, stream>>>(Wi, WiT, D_IMG, P_DIM);
    transpose_cvt<<<dim3(DD_OUT / 64, DD_IN / 64), blk, 0, stream>>>(Wn, WnT, DD_IN, DD_OUT);
    transpose_cvt<<<dim3(DD_OUT / 64, D_IMG / 64), blk, 0, stream>>>(Wim, WimT, D_IMG, DD_OUT);
    transpose_cvt<<<dim3(DD_OUT / 64, (2 * DD_OUT) / 64), blk, 0, stream>>>(Wap, WapT, 2 * DD_OUT, DD_OUT);

    // ---- CSR build ----
    hipMemsetAsync(deg, 0, 2 * N_NODES * sizeof(int), stream);   // deg + cur
    count_deg<<<dim3(E_EDGES / 256), blk, 0, stream>>>(dst, deg);
    scan_deg<<<dim3(1), blk, 0, stream>>>(deg, offs);
    scatter_edges<<<dim3(E_EDGES / 256), blk, 0, stream>>>(src, dst, offs, cur, ssrc);

    // ---- node_proj = h @ Wf + bf ----
    gemm_bf16mfma<true, false, false, true, false><<<dim3(P_DIM / 128, N_NODES / 128), blk, 0, stream>>>(
        h_bf, WfT, bf, nullptr, node_proj, nullptr, N_NODES, P_DIM, DD_IN, 0, 0);
    // ---- img_proj = img_feats @ Wi + bi ----
    gemm_bf16mfma<true, false, false, true, false><<<dim3(P_DIM / 128, (B_EX * R_REG) / 128), blk, 0, stream>>>(
        imgf_bf, WiT, bi, nullptr, img_proj, nullptr, B_EX * R_REG, P_DIM, D_IMG, 0, 0);
    // ---- attention ----
    att_kernel<<<dim3(N_NODES / 4), blk, 0, stream>>>(node_proj, img_proj, batch_ids, Wa, att);
    img_att_kernel<<<dim3(N_NODES), blk, 0, stream>>>(att, img_feats, batch_ids, img_bf);
    // ---- h1 = h @ Wn + bn  -> cat cols 512..1023 (bf16) ----
    gemm_bf16mfma<true, false, false, false, true><<<dim3(DD_OUT / 128, N_NODES / 128), blk, 0, stream>>>(
        h_bf, WnT, bn, nullptr, nullptr, cat, N_NODES, DD_OUT, DD_IN, D_IMG, DD_OUT);
    // ---- neigh = segment_sum(h1[src], dst) via CSR ----
    gather_neigh<<<dim3(N_NODES), blk, 0, stream>>>(offs, ssrc, cat + DD_OUT, neigh);
    // ---- msg = neigh + img @ Wim + bim -> cat cols 0..511 (bf16) ----
    gemm_bf16mfma<true, true, false, false, true><<<dim3(DD_OUT / 128, N_NODES / 128), blk, 0, stream>>>(
        img_bf, WimT, bim, neigh, nullptr, cat, N_NODES, DD_OUT, D_IMG, D_IMG, 0);
    // ---- out = relu(cat @ Wap + bap) ----
    gemm_bf16mfma<true, false, true, true, false><<<dim3(DD_OUT / 128, N_NODES / 128), blk, 0, stream>>>(
        cat, WapT, bap, nullptr, out, nullptr, N_NODES, DD_OUT, 2 * DD_OUT, 0, 0);
}

// Round 3
// 372.242 us; speedup vs baseline: 4.0021x; 1.1681x over previous
//
#include <hip/hip_runtime.h>
#include <cstdint>
#include <cstddef>

#define N_NODES 12288
#define B_EX    64
#define R_REG   36
#define E_EDGES 196608
#define DD_IN   512
#define DD_OUT  512
#define P_DIM   256
#define D_IMG   1024

typedef unsigned short ushort;
typedef __bf16 bf16x8 __attribute__((ext_vector_type(8)));
typedef float f32x4 __attribute__((ext_vector_type(4)));
typedef ushort ushort4v __attribute__((ext_vector_type(4)));
typedef ushort ushort8v __attribute__((ext_vector_type(8)));

__device__ __forceinline__ ushort f2bf(float f) {
    uint32_t u = __float_as_uint(f);
    uint32_t r = (u + 0x7fffu + ((u >> 16) & 1u)) >> 16;
    return (ushort)r;
}
__device__ __forceinline__ float bf2f(ushort u) {
    return __uint_as_float(((uint32_t)u) << 16);
}
__device__ __forceinline__ void gload_lds16(const void* g, void* l) {
    __builtin_amdgcn_global_load_lds((const __attribute__((address_space(1))) void*)g,
                                     (__attribute__((address_space(3))) void*)l, 16, 0, 0);
}
__device__ __forceinline__ float fast_tanh(float x) {
    float t = __expf(2.f * x);
    return 1.f - __fdividef(2.f, t + 1.f);
}

// ================= bf16 MFMA GEMM: C = [Cadd +] A @ BT^T + bias =================
template<bool HAS_BIAS, bool ADD_C, bool RELU, bool OUT_F32, bool OUT_BF16>
__global__ __launch_bounds__(256) void gemm_bf16mfma(
    const ushort* __restrict__ A, const ushort* __restrict__ BT,
    const float* __restrict__ bias, const float* __restrict__ Cadd,
    float* __restrict__ Cf, ushort* __restrict__ Cb,
    int M, int Nn, int K, int ldb, int coloff)
{
    __shared__ ushort As[128 * 64];
    __shared__ ushort Bs[128 * 64];
    const int tid = threadIdx.x;
    const int lane = tid & 63;
    const int wid = tid >> 6;
    const int wm = wid >> 1, wn = wid & 1;
    const int m0 = blockIdx.y * 128, n0 = blockIdx.x * 128;

    f32x4 acc[4][4] = {};

    const int srow = tid >> 3;   // 0..31
    const int schk = tid & 7;    // 16B chunk within 64-elem row
    const char* AsB = (const char*)As;
    const char* BsB = (const char*)Bs;

    for (int k0 = 0; k0 < K; k0 += 64) {
#pragma unroll
        for (int i = 0; i < 4; ++i) {
            int row = i * 32 + srow;
            int ca = (schk ^ (row & 7)) * 8;
            gload_lds16(A + (size_t)(m0 + row) * K + k0 + ca,
                        (char*)As + i * 4096 + wid * 1024);
            int cb = (schk ^ (row & 7)) * 8;
            gload_lds16(BT + (size_t)(n0 + row) * K + k0 + cb,
                        (char*)Bs + i * 4096 + wid * 1024);
        }
        __syncthreads();
#pragma unroll
        for (int kk = 0; kk < 2; ++kk) {
            const int kc = kk * 4 + (lane >> 4);
            bf16x8 af[4], bfr[4];
#pragma unroll
            for (int i = 0; i < 4; ++i) {
                int row = wm * 64 + i * 16 + (lane & 15);
                af[i] = *(const bf16x8*)(AsB + row * 128 + ((kc ^ (row & 7)) << 4));
            }
#pragma unroll
            for (int j = 0; j < 4; ++j) {
                int col = wn * 64 + j * 16 + (lane & 15);
                bfr[j] = *(const bf16x8*)(BsB + col * 128 + ((kc ^ (col & 7)) << 4));
            }
#pragma unroll
            for (int i = 0; i < 4; ++i)
#pragma unroll
                for (int j = 0; j < 4; ++j)
                    acc[i][j] = __builtin_amdgcn_mfma_f32_16x16x32_bf16(af[i], bfr[j], acc[i][j], 0, 0, 0);
        }
        __syncthreads();
    }

#pragma unroll
    for (int i = 0; i < 4; ++i) {
#pragma unroll
        for (int j = 0; j < 4; ++j) {
#pragma unroll
            for (int q = 0; q < 4; ++q) {
                int row = m0 + wm * 64 + i * 16 + (lane >> 4) * 4 + q;
                int col = n0 + wn * 64 + j * 16 + (lane & 15);
                float v = acc[i][j][q];
                if (HAS_BIAS) v += bias[col];
                if (ADD_C)    v += Cadd[(size_t)row * Nn + col];
                if (RELU)     v = fmaxf(v, 0.f);
                if (OUT_F32)  Cf[(size_t)row * Nn + col] = v;
                if (OUT_BF16) Cb[(size_t)row * ldb + col + coloff] = f2bf(v);
            }
        }
    }
}

// ================= fp32 -> bf16 convert =================
__global__ __launch_bounds__(256) void cvt_f32_bf16(
    const float* __restrict__ in, ushort* __restrict__ out, int n4)
{
    int i = blockIdx.x * 256 + threadIdx.x;
    if (i >= n4) return;
    float4 v = ((const float4*)in)[i];
    ushort4v o;
    o[0] = f2bf(v.x); o[1] = f2bf(v.y); o[2] = f2bf(v.z); o[3] = f2bf(v.w);
    ((ushort4v*)out)[i] = o;
}

// ================= W [K][N] fp32 -> WT [N][K] bf16 =================
__global__ __launch_bounds__(256) void transpose_cvt(
    const float* __restrict__ W, ushort* __restrict__ WT, int K, int N)
{
    __shared__ float t[64][65];
    const int n0 = blockIdx.x * 64, k0 = blockIdx.y * 64;
    const int tx = threadIdx.x & 15, ty = threadIdx.x >> 4;
#pragma unroll
    for (int r = 0; r < 4; ++r) {
        float4 v = *(const float4*)&W[(size_t)(k0 + ty * 4 + r) * N + n0 + tx * 4];
        t[ty * 4 + r][tx * 4 + 0] = v.x;
        t[ty * 4 + r][tx * 4 + 1] = v.y;
        t[ty * 4 + r][tx * 4 + 2] = v.z;
        t[ty * 4 + r][tx * 4 + 3] = v.w;
    }
    __syncthreads();
    const int nl = threadIdx.x >> 2, kq = (threadIdx.x & 3) * 16;
    ushort u[16] __attribute__((aligned(16)));
#pragma unroll
    for (int c = 0; c < 16; ++c) u[c] = f2bf(t[kq + c][nl]);
    ushort* d = &WT[(size_t)(n0 + nl) * K + k0 + kq];
    *(ushort8v*)d = *(ushort8v*)&u[0];
    *(ushort8v*)(d + 8) = *(ushort8v*)&u[8];
}

// ================= attention logits + softmax (fast tanh, 1 wave/node) =================
__global__ __launch_bounds__(256) void att_kernel(
    const float* __restrict__ node_proj, const float* __restrict__ img_proj,
    const int* __restrict__ batch_ids, const float* __restrict__ Wa,
    float* __restrict__ att)
{
    const int n = blockIdx.x * 4 + (threadIdx.x >> 6);
    const int lane = threadIdx.x & 63;
    const int b = batch_ids[n];
    const int r = (lane < R_REG) ? lane : 0;
    const float4* np4 = (const float4*)(node_proj + (size_t)n * P_DIM);
    const float4* ip4 = (const float4*)(img_proj + ((size_t)b * R_REG + r) * P_DIM);
    const float4* wa4 = (const float4*)Wa;

    float a0 = 0.f, a1 = 0.f, a2 = 0.f, a3 = 0.f;
#pragma unroll 4
    for (int c = 0; c < P_DIM / 4; ++c) {
        float4 x = np4[c], y = ip4[c], w = wa4[c];
        a0 += fast_tanh(x.x + y.x) * w.x;
        a1 += fast_tanh(x.y + y.y) * w.y;
        a2 += fast_tanh(x.z + y.z) * w.z;
        a3 += fast_tanh(x.w + y.w) * w.w;
    }
    float logit = (a0 + a1) + (a2 + a3);
    if (lane >= R_REG) logit = -INFINITY;

    float m = logit;
#pragma unroll
    for (int off = 32; off; off >>= 1) m = fmaxf(m, __shfl_xor(m, off));
    float e = (lane < R_REG) ? __expf(logit - m) : 0.f;
    float s = e;
#pragma unroll
    for (int off = 32; off; off >>= 1) s += __shfl_xor(s, off);
    if (lane < R_REG) att[(size_t)n * R_REG + lane] = e / s;
}

// ================= batched attended image feature =================
// grid: 64 batches x 2 col-chunks(512) x 8 node-slices. Thread owns 2 cols in regs.
#define IA_SLICES 8
__global__ __launch_bounds__(256) void img_att_batched(
    const float* __restrict__ att, const float* __restrict__ img_feats,
    const int* __restrict__ boffs, const int* __restrict__ nlist,
    ushort* __restrict__ img_bf)
{
    const int b     = blockIdx.x & 63;
    const int chunk = (blockIdx.x >> 6) & 1;
    const int slice = blockIdx.x >> 7;
    const int t = threadIdx.x;
    const int c0 = chunk * 512 + 2 * t;

    const int ns = boffs[b], ne = boffs[b + 1];
    const int cnt = ne - ns;
    const int per = (cnt + IA_SLICES - 1) / IA_SLICES;
    const int i0 = ns + slice * per;
    const int i1 = min(i0 + per, ne);
    if (i0 >= i1) return;   // block-uniform condition

    float2 col[R_REG];
    const float* base = img_feats + (size_t)b * R_REG * D_IMG + c0;
#pragma unroll
    for (int r = 0; r < R_REG; ++r)
        col[r] = *(const float2*)(base + (size_t)r * D_IMG);

    __shared__ float att_s[8][R_REG];
    for (int i = i0; i < i1; i += 8) {
        int g = min(8, i1 - i);
        __syncthreads();
        for (int idx = t; idx < g * R_REG; idx += 256) {
            int j = idx / R_REG, r = idx - j * R_REG;
            att_s[j][r] = att[(size_t)nlist[i + j] * R_REG + r];
        }
        __syncthreads();
        for (int j = 0; j < g; ++j) {
            float4 av[9];
#pragma unroll
            for (int q = 0; q < 9; ++q) av[q] = *(const float4*)&att_s[j][q * 4];
            float ax = 0.f, ay = 0.f;
#pragma unroll
            for (int r = 0; r < R_REG; ++r) {
                float a = (r & 2) ? ((r & 1) ? av[r >> 2].w : av[r >> 2].z)
                                  : ((r & 1) ? av[r >> 2].y : av[r >> 2].x);
                ax += a * col[r].x;
                ay += a * col[r].y;
            }
            ushort2 o; o.x = f2bf(ax); o.y = f2bf(ay);
            *(ushort2*)&img_bf[(size_t)nlist[i + j] * D_IMG + c0] = o;
        }
    }
}

// ================= counting sorts =================
__global__ __launch_bounds__(256) void count_deg(const int* __restrict__ dst, int* __restrict__ deg) {
    int i = blockIdx.x * 256 + threadIdx.x;
    if (i < E_EDGES) atomicAdd(&deg[dst[i]], 1);
}

__global__ __launch_bounds__(256) void scan_deg(const int* __restrict__ deg, int* __restrict__ off) {
    __shared__ int s[257];
    const int t = threadIdx.x;
    const int base = t * 48;
    int sum = 0;
    for (int j = 0; j < 48; ++j) sum += deg[base + j];
    s[t] = sum;
    __syncthreads();
    if (t == 0) {
        int acc = 0;
        for (int i = 0; i < 256; ++i) { int v = s[i]; s[i] = acc; acc += v; }
        s[256] = acc;
    }
    __syncthreads();
    int run = s[t];
    for (int j = 0; j < 48; ++j) { off[base + j] = run; run += deg[base + j]; }
    if (t == 255) off[N_NODES] = s[256];
}

__global__ __launch_bounds__(256) void scatter_edges(
    const int* __restrict__ src, const int* __restrict__ dst,
    const int* __restrict__ off, int* __restrict__ cur, int* __restrict__ ssrc)
{
    int i = blockIdx.x * 256 + threadIdx.x;
    if (i < E_EDGES) {
        int d = dst[i];
        int p = off[d] + atomicAdd(&cur[d], 1);
        ssrc[p] = src[i];
    }
}

__global__ __launch_bounds__(256) void count_batch(const int* __restrict__ bid, int* __restrict__ bcnt) {
    int i = blockIdx.x * 256 + threadIdx.x;
    if (i < N_NODES) atomicAdd(&bcnt[bid[i]], 1);
}

__global__ __launch_bounds__(64) void scan_batch(const int* __restrict__ bcnt, int* __restrict__ boffs) {
    if (threadIdx.x == 0) {
        int acc = 0;
        for (int i = 0; i < B_EX; ++i) { boffs[i] = acc; acc += bcnt[i]; }
        boffs[B_EX] = acc;
    }
}

__global__ __launch_bounds__(256) void scatter_batch(
    const int* __restrict__ bid, const int* __restrict__ boffs,
    int* __restrict__ bcur, int* __restrict__ nlist)
{
    int i = blockIdx.x * 256 + threadIdx.x;
    if (i < N_NODES) {
        int b = bid[i];
        int p = boffs[b] + atomicAdd(&bcur[b], 1);
        nlist[p] = i;
    }
}

// ================= CSR gather: neigh[n] = sum over in-edges of h1[src] =================
__global__ __launch_bounds__(256) void gather_neigh(
    const int* __restrict__ off, const int* __restrict__ ssrc,
    const ushort* __restrict__ h1b /* cat+512, ld 1024 */, float* __restrict__ neigh)
{
    const int n = blockIdx.x, t = threadIdx.x;
    const int e0 = off[n], e1 = off[n + 1];
    float a0 = 0.f, a1 = 0.f;
    for (int e = e0; e < e1; ++e) {
        const uint32_t* row = (const uint32_t*)(h1b + (size_t)ssrc[e] * 1024);
        uint32_t v = row[t];
        a0 += bf2f((ushort)(v & 0xffffu));
        a1 += bf2f((ushort)(v >> 16));
    }
    float2 o; o.x = a0; o.y = a1;
    *(float2*)&neigh[(size_t)n * DD_OUT + 2 * t] = o;
}

extern "C" void kernel_launch(void* const* d_in, const int* in_sizes, int n_in,
                              void* d_out, int out_size, void* d_ws, size_t ws_size,
                              hipStream_t stream) {
    const float* h         = (const float*)d_in[0];
    const float* img_feats = (const float*)d_in[1];
    const int*   batch_ids = (const int*)d_in[2];
    const int*   src       = (const int*)d_in[3];
    const int*   dst       = (const int*)d_in[4];
    const float* Wf  = (const float*)d_in[5];
    const float* bf  = (const float*)d_in[6];
    const float* Wi  = (const float*)d_in[7];
    const float* bi  = (const float*)d_in[8];
    const float* Wa  = (const float*)d_in[9];
    const float* Wn  = (const float*)d_in[11];
    const float* bn  = (const float*)d_in[12];
    const float* Wim = (const float*)d_in[13];
    const float* bim = (const float*)d_in[14];
    const float* Wap = (const float*)d_in[15];
    const float* bap = (const float*)d_in[16];
    float* out = (float*)d_out;
    float* ws  = (float*)d_ws;

    // ---- workspace layout (offsets in 4-byte units) ----
    ushort* h_bf    = (ushort*)(ws + 0);         // [12288][512] bf16
    ushort* img_bf  = (ushort*)(ws + 3145728);   // [12288][1024] bf16
    float*  node_proj = ws + 9437184;            // [12288][256] f32
    float*  img_proj  = ws + 12582912;           // [2304][256]  f32
    ushort* imgf_bf   = (ushort*)(ws + 13172736);// [2304][1024] bf16
    float*  att       = ws + 14352384;           // [12288][36]  f32
    float*  neigh     = ws + 9437184;            // [12288][512] f32 (overlays node_proj region)
    ushort* cat       = (ushort*)(ws + 15728640);// [12288][1024] bf16: cols 0-511 msg, 512-1023 h1
    ushort* WfT  = (ushort*)(ws + 22020096);     // [256][512]
    ushort* WiT  = (ushort*)(ws + 22085632);     // [256][1024]
    ushort* WnT  = (ushort*)(ws + 22216704);     // [512][512]
    ushort* WimT = (ushort*)(ws + 22347776);     // [512][1024]
    ushort* WapT = (ushort*)(ws + 22609920);     // [512][1024]
    int* deg  = (int*)(ws + 22872064);           // [12288]
    int* cur  = deg + N_NODES;                   // [12288]
    int* offs = cur + N_NODES;                   // [12289]
    int* ssrc = offs + N_NODES + 1;              // [196608]
    int* bcnt = ssrc + E_EDGES;                  // [64]
    int* bcur = bcnt + B_EX;                     // [64]
    int* boffs = bcur + B_EX;                    // [65]
    int* nlist = boffs + B_EX + 1;               // [12288]

    dim3 blk(256);

    // ---- converts & weight transposes ----
    cvt_f32_bf16<<<dim3((N_NODES * DD_IN / 4 + 255) / 256), blk, 0, stream>>>(h, h_bf, N_NODES * DD_IN / 4);
    cvt_f32_bf16<<<dim3((B_EX * R_REG * D_IMG / 4 + 255) / 256), blk, 0, stream>>>(img_feats, imgf_bf, B_EX * R_REG * D_IMG / 4);
    transpose_cvt<<<dim3(P_DIM / 64, DD_IN / 64), blk, 0, stream>>>(Wf, WfT, DD_IN, P_DIM);
    transpose_cvt<<<dim3(P_DIM / 64, D_IMG / 64), blk, 0, stream>>>(Wi, WiT, D_IMG, P_DIM);
    transpose_cvt<<<dim3(DD_OUT / 64, DD_IN / 64), blk, 0, stream>>>(Wn, WnT, DD_IN, DD_OUT);
    transpose_cvt<<<dim3(DD_OUT / 64, D_IMG / 64), blk, 0, stream>>>(Wim, WimT, D_IMG, DD_OUT);
    transpose_cvt<<<dim3(DD_OUT / 64, (2 * DD_OUT) / 64), blk, 0, stream>>>(Wap, WapT, 2 * DD_OUT, DD_OUT);

    // ---- CSR build (edges by dst) + node sort by batch ----
    hipMemsetAsync(deg, 0, 2 * N_NODES * sizeof(int), stream);
    hipMemsetAsync(bcnt, 0, 2 * B_EX * sizeof(int), stream);
    count_deg<<<dim3(E_EDGES / 256), blk, 0, stream>>>(dst, deg);
    scan_deg<<<dim3(1), blk, 0, stream>>>(deg, offs);
    scatter_edges<<<dim3(E_EDGES / 256), blk, 0, stream>>>(src, dst, offs, cur, ssrc);
    count_batch<<<dim3(N_NODES / 256), blk, 0, stream>>>(batch_ids, bcnt);
    scan_batch<<<dim3(1), dim3(64), 0, stream>>>(bcnt, boffs);
    scatter_batch<<<dim3(N_NODES / 256), blk, 0, stream>>>(batch_ids, boffs, bcur, nlist);

    // ---- node_proj = h @ Wf + bf ----
    gemm_bf16mfma<true, false, false, true, false><<<dim3(P_DIM / 128, N_NODES / 128), blk, 0, stream>>>(
        h_bf, WfT, bf, nullptr, node_proj, nullptr, N_NODES, P_DIM, DD_IN, 0, 0);
    // ---- img_proj = img_feats @ Wi + bi ----
    gemm_bf16mfma<true, false, false, true, false><<<dim3(P_DIM / 128, (B_EX * R_REG) / 128), blk, 0, stream>>>(
        imgf_bf, WiT, bi, nullptr, img_proj, nullptr, B_EX * R_REG, P_DIM, D_IMG, 0, 0);
    // ---- attention ----
    att_kernel<<<dim3(N_NODES / 4), blk, 0, stream>>>(node_proj, img_proj, batch_ids, Wa, att);
    img_att_batched<<<dim3(B_EX * 2 * IA_SLICES), blk, 0, stream>>>(att, img_feats, boffs, nlist, img_bf);
    // ---- h1 = h @ Wn + bn  -> cat cols 512..1023 (bf16) ----
    gemm_bf16mfma<true, false, false, false, true><<<dim3(DD_OUT / 128, N_NODES / 128), blk, 0, stream>>>(
        h_bf, WnT, bn, nullptr, nullptr, cat, N_NODES, DD_OUT, DD_IN, D_IMG, DD_OUT);
    // ---- neigh = segment_sum(h1[src], dst) via CSR ----
    gather_neigh<<<dim3(N_NODES), blk, 0, stream>>>(offs, ssrc, cat + DD_OUT, neigh);
    // ---- msg = neigh + img @ Wim + bim -> cat cols 0..511 (bf16) ----
    gemm_bf16mfma<true, true, false, false, true><<<dim3(DD_OUT / 128, N_NODES / 128), blk, 0, stream>>>(
        img_bf, WimT, bim, neigh, nullptr, cat, N_NODES, DD_OUT, D_IMG, D_IMG, 0);
    // ---- out = relu(cat @ Wap + bap) ----
    gemm_bf16mfma<true, false, true, true, false><<<dim3(DD_OUT / 128, N_NODES / 128), blk, 0, stream>>>(
        cat, WapT, bap, nullptr, out, nullptr, N_NODES, DD_OUT, 2 * DD_OUT, 0, 0);
}

// Round 4
// 336.538 us; speedup vs baseline: 4.4266x; 1.1061x over previous
//
#include <hip/hip_runtime.h>
#include <cstdint>
#include <cstddef>

#define N_NODES 12288
#define B_EX    64
#define R_REG   36
#define E_EDGES 196608
#define DD_IN   512
#define DD_OUT  512
#define P_DIM   256
#define D_IMG   1024

typedef unsigned short ushort;
typedef __bf16 bf16x8 __attribute__((ext_vector_type(8)));
typedef float f32x4 __attribute__((ext_vector_type(4)));
typedef ushort ushort4v __attribute__((ext_vector_type(4)));
typedef ushort ushort8v __attribute__((ext_vector_type(8)));

__device__ __forceinline__ ushort f2bf(float f) {
    uint32_t u = __float_as_uint(f);
    uint32_t r = (u + 0x7fffu + ((u >> 16) & 1u)) >> 16;
    return (ushort)r;
}
__device__ __forceinline__ float bf2f(ushort u) {
    return __uint_as_float(((uint32_t)u) << 16);
}
__device__ __forceinline__ void gload_lds16(const void* g, void* l) {
    __builtin_amdgcn_global_load_lds((const __attribute__((address_space(1))) void*)g,
                                     (__attribute__((address_space(3))) void*)l, 16, 0, 0);
}
__device__ __forceinline__ float fast_tanh(float x) {
    float t = __expf(2.f * x);
    return 1.f - __fdividef(2.f, t + 1.f);
}

// ================= bf16 MFMA GEMM: C = [Cadd +] A @ BT^T + bias =================
template<bool HAS_BIAS, bool ADD_C, bool RELU, bool OUT_F32, bool OUT_BF16>
__global__ __launch_bounds__(256) void gemm_bf16mfma(
    const ushort* __restrict__ A, const ushort* __restrict__ BT,
    const float* __restrict__ bias, const float* __restrict__ Cadd,
    float* __restrict__ Cf, ushort* __restrict__ Cb,
    int M, int Nn, int K, int ldb, int coloff)
{
    __shared__ ushort As[128 * 64];
    __shared__ ushort Bs[128 * 64];
    const int tid = threadIdx.x;
    const int lane = tid & 63;
    const int wid = tid >> 6;
    const int wm = wid >> 1, wn = wid & 1;
    const int m0 = blockIdx.y * 128, n0 = blockIdx.x * 128;

    f32x4 acc[4][4] = {};

    const int srow = tid >> 3;   // 0..31
    const int schk = tid & 7;    // 16B chunk within 64-elem row
    const char* AsB = (const char*)As;
    const char* BsB = (const char*)Bs;

    for (int k0 = 0; k0 < K; k0 += 64) {
#pragma unroll
        for (int i = 0; i < 4; ++i) {
            int row = i * 32 + srow;
            int ca = (schk ^ (row & 7)) * 8;
            gload_lds16(A + (size_t)(m0 + row) * K + k0 + ca,
                        (char*)As + i * 4096 + wid * 1024);
            int cb = (schk ^ (row & 7)) * 8;
            gload_lds16(BT + (size_t)(n0 + row) * K + k0 + cb,
                        (char*)Bs + i * 4096 + wid * 1024);
        }
        __syncthreads();
#pragma unroll
        for (int kk = 0; kk < 2; ++kk) {
            const int kc = kk * 4 + (lane >> 4);
            bf16x8 af[4], bfr[4];
#pragma unroll
            for (int i = 0; i < 4; ++i) {
                int row = wm * 64 + i * 16 + (lane & 15);
                af[i] = *(const bf16x8*)(AsB + row * 128 + ((kc ^ (row & 7)) << 4));
            }
#pragma unroll
            for (int j = 0; j < 4; ++j) {
                int col = wn * 64 + j * 16 + (lane & 15);
                bfr[j] = *(const bf16x8*)(BsB + col * 128 + ((kc ^ (col & 7)) << 4));
            }
#pragma unroll
            for (int i = 0; i < 4; ++i)
#pragma unroll
                for (int j = 0; j < 4; ++j)
                    acc[i][j] = __builtin_amdgcn_mfma_f32_16x16x32_bf16(af[i], bfr[j], acc[i][j], 0, 0, 0);
        }
        __syncthreads();
    }

#pragma unroll
    for (int i = 0; i < 4; ++i) {
#pragma unroll
        for (int j = 0; j < 4; ++j) {
#pragma unroll
            for (int q = 0; q < 4; ++q) {
                int row = m0 + wm * 64 + i * 16 + (lane >> 4) * 4 + q;
                int col = n0 + wn * 64 + j * 16 + (lane & 15);
                float v = acc[i][j][q];
                if (HAS_BIAS) v += bias[col];
                if (ADD_C)    v += Cadd[(size_t)row * Nn + col];
                if (RELU)     v = fmaxf(v, 0.f);
                if (OUT_F32)  Cf[(size_t)row * Nn + col] = v;
                if (OUT_BF16) Cb[(size_t)row * ldb + col + coloff] = f2bf(v);
            }
        }
    }
}

// ================= fp32 -> bf16 convert =================
__global__ __launch_bounds__(256) void cvt_f32_bf16(
    const float* __restrict__ in, ushort* __restrict__ out, int n4)
{
    int i = blockIdx.x * 256 + threadIdx.x;
    if (i >= n4) return;
    float4 v = ((const float4*)in)[i];
    ushort4v o;
    o[0] = f2bf(v.x); o[1] = f2bf(v.y); o[2] = f2bf(v.z); o[3] = f2bf(v.w);
    ((ushort4v*)out)[i] = o;
}

// ================= W [K][N] fp32 -> WT [N][K] bf16 =================
__global__ __launch_bounds__(256) void transpose_cvt(
    const float* __restrict__ W, ushort* __restrict__ WT, int K, int N)
{
    __shared__ float t[64][65];
    const int n0 = blockIdx.x * 64, k0 = blockIdx.y * 64;
    const int tx = threadIdx.x & 15, ty = threadIdx.x >> 4;
#pragma unroll
    for (int r = 0; r < 4; ++r) {
        float4 v = *(const float4*)&W[(size_t)(k0 + ty * 4 + r) * N + n0 + tx * 4];
        t[ty * 4 + r][tx * 4 + 0] = v.x;
        t[ty * 4 + r][tx * 4 + 1] = v.y;
        t[ty * 4 + r][tx * 4 + 2] = v.z;
        t[ty * 4 + r][tx * 4 + 3] = v.w;
    }
    __syncthreads();
    const int nl = threadIdx.x >> 2, kq = (threadIdx.x & 3) * 16;
    ushort u[16] __attribute__((aligned(16)));
#pragma unroll
    for (int c = 0; c < 16; ++c) u[c] = f2bf(t[kq + c][nl]);
    ushort* d = &WT[(size_t)(n0 + nl) * K + k0 + kq];
    *(ushort8v*)d = *(ushort8v*)&u[0];
    *(ushort8v*)(d + 8) = *(ushort8v*)&u[8];
}

// ================= attention logits + softmax =================
// Wave = node. Lane = 4 consecutive channels (coalesced). Per region r:
// coalesced float4 load of img_proj row, 4x fast_tanh + fma, butterfly reduce,
// logit lands in lane r. Then softmax over lanes 0..35.
__global__ __launch_bounds__(256) void att_kernel(
    const float* __restrict__ node_proj, const float* __restrict__ img_proj,
    const int* __restrict__ batch_ids, const float* __restrict__ Wa,
    float* __restrict__ att)
{
    const int n = blockIdx.x * 4 + (threadIdx.x >> 6);
    const int lane = threadIdx.x & 63;
    const int b = batch_ids[n];

    const float4 np = *(const float4*)(node_proj + (size_t)n * P_DIM + 4 * lane);
    const float4 wa = *(const float4*)(Wa + 4 * lane);
    const float* ip0 = img_proj + (size_t)b * R_REG * P_DIM + 4 * lane;

    float mylogit = -INFINITY;
#pragma unroll 4
    for (int r = 0; r < R_REG; ++r) {
        float4 ip = *(const float4*)(ip0 + (size_t)r * P_DIM);
        float s = fast_tanh(np.x + ip.x) * wa.x;
        s += fast_tanh(np.y + ip.y) * wa.y;
        s += fast_tanh(np.z + ip.z) * wa.z;
        s += fast_tanh(np.w + ip.w) * wa.w;
#pragma unroll
        for (int off = 32; off; off >>= 1) s += __shfl_xor(s, off);
        if (lane == r) mylogit = s;
    }

    float m = mylogit;
#pragma unroll
    for (int off = 32; off; off >>= 1) m = fmaxf(m, __shfl_xor(m, off));
    float e = (lane < R_REG) ? __expf(mylogit - m) : 0.f;
    float s = e;
#pragma unroll
    for (int off = 32; off; off >>= 1) s += __shfl_xor(s, off);
    if (lane < R_REG) att[(size_t)n * R_REG + lane] = e / s;
}

// ================= batched attended image feature =================
#define IA_SLICES 8
__global__ __launch_bounds__(256) void img_att_batched(
    const float* __restrict__ att, const float* __restrict__ img_feats,
    const int* __restrict__ boffs, const int* __restrict__ nlist,
    ushort* __restrict__ img_bf)
{
    const int b     = blockIdx.x & 63;
    const int chunk = (blockIdx.x >> 6) & 1;
    const int slice = blockIdx.x >> 7;
    const int t = threadIdx.x;
    const int c0 = chunk * 512 + 2 * t;

    const int ns = boffs[b], ne = boffs[b + 1];
    const int cnt = ne - ns;
    const int per = (cnt + IA_SLICES - 1) / IA_SLICES;
    const int i0 = ns + slice * per;
    const int i1 = min(i0 + per, ne);
    if (i0 >= i1) return;

    float2 col[R_REG];
    const float* base = img_feats + (size_t)b * R_REG * D_IMG + c0;
#pragma unroll
    for (int r = 0; r < R_REG; ++r)
        col[r] = *(const float2*)(base + (size_t)r * D_IMG);

    __shared__ float att_s[8][R_REG];
    for (int i = i0; i < i1; i += 8) {
        int g = min(8, i1 - i);
        __syncthreads();
        for (int idx = t; idx < g * R_REG; idx += 256) {
            int j = idx / R_REG, r = idx - j * R_REG;
            att_s[j][r] = att[(size_t)nlist[i + j] * R_REG + r];
        }
        __syncthreads();
        for (int j = 0; j < g; ++j) {
            float4 av[9];
#pragma unroll
            for (int q = 0; q < 9; ++q) av[q] = *(const float4*)&att_s[j][q * 4];
            float ax = 0.f, ay = 0.f;
#pragma unroll
            for (int r = 0; r < R_REG; ++r) {
                float a = (r & 2) ? ((r & 1) ? av[r >> 2].w : av[r >> 2].z)
                                  : ((r & 1) ? av[r >> 2].y : av[r >> 2].x);
                ax += a * col[r].x;
                ay += a * col[r].y;
            }
            ushort2 o; o.x = f2bf(ax); o.y = f2bf(ay);
            *(ushort2*)&img_bf[(size_t)nlist[i + j] * D_IMG + c0] = o;
        }
    }
}

// ================= counting sorts =================
__global__ __launch_bounds__(256) void count_deg(const int* __restrict__ dst, int* __restrict__ deg) {
    int i = blockIdx.x * 256 + threadIdx.x;
    if (i < E_EDGES) atomicAdd(&deg[dst[i]], 1);
}

__global__ __launch_bounds__(256) void scan_deg(const int* __restrict__ deg, int* __restrict__ off) {
    __shared__ int s[257];
    const int t = threadIdx.x;
    const int base = t * 48;
    int sum = 0;
    for (int j = 0; j < 48; ++j) sum += deg[base + j];
    s[t] = sum;
    __syncthreads();
    if (t == 0) {
        int acc = 0;
        for (int i = 0; i < 256; ++i) { int v = s[i]; s[i] = acc; acc += v; }
        s[256] = acc;
    }
    __syncthreads();
    int run = s[t];
    for (int j = 0; j < 48; ++j) { off[base + j] = run; run += deg[base + j]; }
    if (t == 255) off[N_NODES] = s[256];
}

__global__ __launch_bounds__(256) void scatter_edges(
    const int* __restrict__ src, const int* __restrict__ dst,
    const int* __restrict__ off, int* __restrict__ cur, int* __restrict__ ssrc)
{
    int i = blockIdx.x * 256 + threadIdx.x;
    if (i < E_EDGES) {
        int d = dst[i];
        int p = off[d] + atomicAdd(&cur[d], 1);
        ssrc[p] = src[i];
    }
}

__global__ __launch_bounds__(256) void count_batch(const int* __restrict__ bid, int* __restrict__ bcnt) {
    int i = blockIdx.x * 256 + threadIdx.x;
    if (i < N_NODES) atomicAdd(&bcnt[bid[i]], 1);
}

__global__ __launch_bounds__(64) void scan_batch(const int* __restrict__ bcnt, int* __restrict__ boffs) {
    if (threadIdx.x == 0) {
        int acc = 0;
        for (int i = 0; i < B_EX; ++i) { boffs[i] = acc; acc += bcnt[i]; }
        boffs[B_EX] = acc;
    }
}

__global__ __launch_bounds__(256) void scatter_batch(
    const int* __restrict__ bid, const int* __restrict__ boffs,
    int* __restrict__ bcur, int* __restrict__ nlist)
{
    int i = blockIdx.x * 256 + threadIdx.x;
    if (i < N_NODES) {
        int b = bid[i];
        int p = boffs[b] + atomicAdd(&bcur[b], 1);
        nlist[p] = i;
    }
}

// ================= CSR gather: neigh[n] = sum over in-edges of h1[src] =================
__global__ __launch_bounds__(256) void gather_neigh(
    const int* __restrict__ off, const int* __restrict__ ssrc,
    const ushort* __restrict__ h1b /* cat+512, ld 1024 */, float* __restrict__ neigh)
{
    const int n = blockIdx.x, t = threadIdx.x;
    const int e0 = off[n], e1 = off[n + 1];
    float a0 = 0.f, a1 = 0.f;
    for (int e = e0; e < e1; ++e) {
        const uint32_t* row = (const uint32_t*)(h1b + (size_t)ssrc[e] * 1024);
        uint32_t v = row[t];
        a0 += bf2f((ushort)(v & 0xffffu));
        a1 += bf2f((ushort)(v >> 16));
    }
    float2 o; o.x = a0; o.y = a1;
    *(float2*)&neigh[(size_t)n * DD_OUT + 2 * t] = o;
}

extern "C" void kernel_launch(void* const* d_in, const int* in_sizes, int n_in,
                              void* d_out, int out_size, void* d_ws, size_t ws_size,
                              hipStream_t stream) {
    const float* h         = (const float*)d_in[0];
    const float* img_feats = (const float*)d_in[1];
    const int*   batch_ids = (const int*)d_in[2];
    const int*   src       = (const int*)d_in[3];
    const int*   dst       = (const int*)d_in[4];
    const float* Wf  = (const float*)d_in[5];
    const float* bf  = (const float*)d_in[6];
    const float* Wi  = (const float*)d_in[7];
    const float* bi  = (const float*)d_in[8];
    const float* Wa  = (const float*)d_in[9];
    const float* Wn  = (const float*)d_in[11];
    const float* bn  = (const float*)d_in[12];
    const float* Wim = (const float*)d_in[13];
    const float* bim = (const float*)d_in[14];
    const float* Wap = (const float*)d_in[15];
    const float* bap = (const float*)d_in[16];
    float* out = (float*)d_out;
    float* ws  = (float*)d_ws;

    // ---- workspace layout (offsets in 4-byte units) ----
    ushort* h_bf    = (ushort*)(ws + 0);         // [12288][512] bf16
    ushort* img_bf  = (ushort*)(ws + 3145728);   // [12288][1024] bf16
    float*  node_proj = ws + 9437184;            // [12288][256] f32
    float*  img_proj  = ws + 12582912;           // [2304][256]  f32
    ushort* imgf_bf   = (ushort*)(ws + 13172736);// [2304][1024] bf16
    float*  att       = ws + 14352384;           // [12288][36]  f32
    float*  neigh     = ws + 9437184;            // [12288][512] f32 (overlays node_proj region)
    ushort* cat       = (ushort*)(ws + 15728640);// [12288][1024] bf16: cols 0-511 msg, 512-1023 h1
    ushort* WfT  = (ushort*)(ws + 22020096);     // [256][512]
    ushort* WiT  = (ushort*)(ws + 22085632);     // [256][1024]
    ushort* WnT  = (ushort*)(ws + 22216704);     // [512][512]
    ushort* WimT = (ushort*)(ws + 22347776);     // [512][1024]
    ushort* WapT = (ushort*)(ws + 22609920);     // [512][1024]
    int* deg  = (int*)(ws + 22872064);           // [12288]
    int* cur  = deg + N_NODES;                   // [12288]
    int* offs = cur + N_NODES;                   // [12289]
    int* ssrc = offs + N_NODES + 1;              // [196608]
    int* bcnt = ssrc + E_EDGES;                  // [64]
    int* bcur = bcnt + B_EX;                     // [64]
    int* boffs = bcur + B_EX;                    // [65]
    int* nlist = boffs + B_EX + 1;               // [12288]

    dim3 blk(256);

    // ---- converts & weight transposes ----
    cvt_f32_bf16<<<dim3((N_NODES * DD_IN / 4 + 255) / 256), blk, 0, stream>>>(h, h_bf, N_NODES * DD_IN / 4);
    cvt_f32_bf16<<<dim3((B_EX * R_REG * D_IMG / 4 + 255) / 256), blk, 0, stream>>>(img_feats, imgf_bf, B_EX * R_REG * D_IMG / 4);
    transpose_cvt<<<dim3(P_DIM / 64, DD_IN / 64), blk, 0, stream>>>(Wf, WfT, DD_IN, P_DIM);
    transpose_cvt<<<dim3(P_DIM / 64, D_IMG / 64), blk, 0, stream>>>(Wi, WiT, D_IMG, P_DIM);
    transpose_cvt<<<dim3(DD_OUT / 64, DD_IN / 64), blk, 0, stream>>>(Wn, WnT, DD_IN, DD_OUT);
    transpose_cvt<<<dim3(DD_OUT / 64, D_IMG / 64), blk, 0, stream>>>(Wim, WimT, D_IMG, DD_OUT);
    transpose_cvt<<<dim3(DD_OUT / 64, (2 * DD_OUT) / 64), blk, 0, stream>>>(Wap, WapT, 2 * DD_OUT, DD_OUT);

    // ---- CSR build (edges by dst) + node sort by batch ----
    hipMemsetAsync(deg, 0, 2 * N_NODES * sizeof(int), stream);
    hipMemsetAsync(bcnt, 0, 2 * B_EX * sizeof(int), stream);
    count_deg<<<dim3(E_EDGES / 256), blk, 0, stream>>>(dst, deg);
    scan_deg<<<dim3(1), blk, 0, stream>>>(deg, offs);
    scatter_edges<<<dim3(E_EDGES / 256), blk, 0, stream>>>(src, dst, offs, cur, ssrc);
    count_batch<<<dim3(N_NODES / 256), blk, 0, stream>>>(batch_ids, bcnt);
    scan_batch<<<dim3(1), dim3(64), 0, stream>>>(bcnt, boffs);
    scatter_batch<<<dim3(N_NODES / 256), blk, 0, stream>>>(batch_ids, boffs, bcur, nlist);

    // ---- node_proj = h @ Wf + bf ----
    gemm_bf16mfma<true, false, false, true, false><<<dim3(P_DIM / 128, N_NODES / 128), blk, 0, stream>>>(
        h_bf, WfT, bf, nullptr, node_proj, nullptr, N_NODES, P_DIM, DD_IN, 0, 0);
    // ---- img_proj = img_feats @ Wi + bi ----
    gemm_bf16mfma<true, false, false, true, false><<<dim3(P_DIM / 128, (B_EX * R_REG) / 128), blk, 0, stream>>>(
        imgf_bf, WiT, bi, nullptr, img_proj, nullptr, B_EX * R_REG, P_DIM, D_IMG, 0, 0);
    // ---- attention ----
    att_kernel<<<dim3(N_NODES / 4), blk, 0, stream>>>(node_proj, img_proj, batch_ids, Wa, att);
    img_att_batched<<<dim3(B_EX * 2 * IA_SLICES), blk, 0, stream>>>(att, img_feats, boffs, nlist, img_bf);
    // ---- h1 = h @ Wn + bn  -> cat cols 512..1023 (bf16) ----
    gemm_bf16mfma<true, false, false, false, true><<<dim3(DD_OUT / 128, N_NODES / 128), blk, 0, stream>>>(
        h_bf, WnT, bn, nullptr, nullptr, cat, N_NODES, DD_OUT, DD_IN, D_IMG, DD_OUT);
    // ---- neigh = segment_sum(h1[src], dst) via CSR ----
    gather_neigh<<<dim3(N_NODES), blk, 0, stream>>>(offs, ssrc, cat + DD_OUT, neigh);
    // ---- msg = neigh + img @ Wim + bim -> cat cols 0..511 (bf16) ----
    gemm_bf16mfma<true, true, false, false, true><<<dim3(DD_OUT / 128, N_NODES / 128), blk, 0, stream>>>(
        img_bf, WimT, bim, neigh, nullptr, cat, N_NODES, DD_OUT, D_IMG, D_IMG, 0);
    // ---- out = relu(cat @ Wap + bap) ----
    gemm_bf16mfma<true, false, true, true, false><<<dim3(DD_OUT / 128, N_NODES / 128), blk, 0, stream>>>(
        cat, WapT, bap, nullptr, out, nullptr, N_NODES, DD_OUT, 2 * DD_OUT, 0, 0);
}

// Round 5
// 298.899 us; speedup vs baseline: 4.9841x; 1.1259x over previous
//
#include <hip/hip_runtime.h>
#include <cstdint>
#include <cstddef>

#define N_NODES 12288
#define B_EX    64
#define R_REG   36
#define E_EDGES 196608
#define DD_IN   512
#define DD_OUT  512
#define P_DIM   256
#define D_IMG   1024
#define TANH_C  2.885390081777927f   // 2*log2(e)

typedef unsigned short ushort;
typedef __bf16 bf16x8 __attribute__((ext_vector_type(8)));
typedef float f32x4 __attribute__((ext_vector_type(4)));
typedef ushort ushort4v __attribute__((ext_vector_type(4)));
typedef ushort ushort8v __attribute__((ext_vector_type(8)));

__device__ __forceinline__ ushort f2bf(float f) {
    uint32_t u = __float_as_uint(f);
    uint32_t r = (u + 0x7fffu + ((u >> 16) & 1u)) >> 16;
    return (ushort)r;
}
__device__ __forceinline__ float bf2f(ushort u) {
    return __uint_as_float(((uint32_t)u) << 16);
}
__device__ __forceinline__ void gload_lds16(const void* g, void* l) {
    __builtin_amdgcn_global_load_lds((const __attribute__((address_space(1))) void*)g,
                                     (__attribute__((address_space(3))) void*)l, 16, 0, 0);
}
__device__ __forceinline__ float fexp2(float x) {   // 2^x
    float r; asm("v_exp_f32 %0, %1" : "=v"(r) : "v"(x)); return r;
}
__device__ __forceinline__ float frcp(float x) {    // 1/x
    float r; asm("v_rcp_f32 %0, %1" : "=v"(r) : "v"(x)); return r;
}

// ================= bf16 MFMA GEMM: C = [Cadd +] A @ BT^T + bias =================
template<bool HAS_BIAS, bool ADD_C, bool RELU, bool OUT_F32, bool OUT_BF16>
__global__ __launch_bounds__(256) void gemm_bf16mfma(
    const ushort* __restrict__ A, const ushort* __restrict__ BT,
    const float* __restrict__ bias, const float* __restrict__ Cadd,
    float* __restrict__ Cf, ushort* __restrict__ Cb,
    int M, int Nn, int K, int ldb, int coloff)
{
    __shared__ ushort As[128 * 64];
    __shared__ ushort Bs[128 * 64];
    const int tid = threadIdx.x;
    const int lane = tid & 63;
    const int wid = tid >> 6;
    const int wm = wid >> 1, wn = wid & 1;
    const int m0 = blockIdx.y * 128, n0 = blockIdx.x * 128;

    f32x4 acc[4][4] = {};

    const int srow = tid >> 3;
    const int schk = tid & 7;
    const char* AsB = (const char*)As;
    const char* BsB = (const char*)Bs;

    for (int k0 = 0; k0 < K; k0 += 64) {
#pragma unroll
        for (int i = 0; i < 4; ++i) {
            int row = i * 32 + srow;
            int ca = (schk ^ (row & 7)) * 8;
            gload_lds16(A + (size_t)(m0 + row) * K + k0 + ca,
                        (char*)As + i * 4096 + wid * 1024);
            int cb = (schk ^ (row & 7)) * 8;
            gload_lds16(BT + (size_t)(n0 + row) * K + k0 + cb,
                        (char*)Bs + i * 4096 + wid * 1024);
        }
        __syncthreads();
#pragma unroll
        for (int kk = 0; kk < 2; ++kk) {
            const int kc = kk * 4 + (lane >> 4);
            bf16x8 af[4], bfr[4];
#pragma unroll
            for (int i = 0; i < 4; ++i) {
                int row = wm * 64 + i * 16 + (lane & 15);
                af[i] = *(const bf16x8*)(AsB + row * 128 + ((kc ^ (row & 7)) << 4));
            }
#pragma unroll
            for (int j = 0; j < 4; ++j) {
                int col = wn * 64 + j * 16 + (lane & 15);
                bfr[j] = *(const bf16x8*)(BsB + col * 128 + ((kc ^ (col & 7)) << 4));
            }
#pragma unroll
            for (int i = 0; i < 4; ++i)
#pragma unroll
                for (int j = 0; j < 4; ++j)
                    acc[i][j] = __builtin_amdgcn_mfma_f32_16x16x32_bf16(af[i], bfr[j], acc[i][j], 0, 0, 0);
        }
        __syncthreads();
    }

#pragma unroll
    for (int i = 0; i < 4; ++i) {
#pragma unroll
        for (int j = 0; j < 4; ++j) {
#pragma unroll
            for (int q = 0; q < 4; ++q) {
                int row = m0 + wm * 64 + i * 16 + (lane >> 4) * 4 + q;
                int col = n0 + wn * 64 + j * 16 + (lane & 15);
                float v = acc[i][j][q];
                if (HAS_BIAS) v += bias[col];
                if (ADD_C)    v += Cadd[(size_t)row * Nn + col];
                if (RELU)     v = fmaxf(v, 0.f);
                if (OUT_F32)  Cf[(size_t)row * Nn + col] = v;
                if (OUT_BF16) Cb[(size_t)row * ldb + col + coloff] = f2bf(v);
            }
        }
    }
}

// ========== fused first GEMM: A=h_bf [12288][512], BT=[WfT;WnT] [768][512] ==========
// cols 0..255  -> node_proj_s = (acc + bf)*TANH_C   (f32, pre-scaled for att)
// cols 256..767-> cat[row][512 + col-256] = bf16(acc + bn)
__global__ __launch_bounds__(256) void gemm_fused_first(
    const ushort* __restrict__ A, const ushort* __restrict__ BT,
    const float* __restrict__ biasF, const float* __restrict__ biasN,
    float* __restrict__ node_proj_s, ushort* __restrict__ cat)
{
    __shared__ ushort As[128 * 64];
    __shared__ ushort Bs[128 * 64];
    const int K = DD_IN;
    const int tid = threadIdx.x;
    const int lane = tid & 63;
    const int wid = tid >> 6;
    const int wm = wid >> 1, wn = wid & 1;
    const int m0 = blockIdx.y * 128, n0 = blockIdx.x * 128;

    f32x4 acc[4][4] = {};

    const int srow = tid >> 3;
    const int schk = tid & 7;
    const char* AsB = (const char*)As;
    const char* BsB = (const char*)Bs;

    for (int k0 = 0; k0 < K; k0 += 64) {
#pragma unroll
        for (int i = 0; i < 4; ++i) {
            int row = i * 32 + srow;
            int ca = (schk ^ (row & 7)) * 8;
            gload_lds16(A + (size_t)(m0 + row) * K + k0 + ca,
                        (char*)As + i * 4096 + wid * 1024);
            gload_lds16(BT + (size_t)(n0 + row) * K + k0 + ca,
                        (char*)Bs + i * 4096 + wid * 1024);
        }
        __syncthreads();
#pragma unroll
        for (int kk = 0; kk < 2; ++kk) {
            const int kc = kk * 4 + (lane >> 4);
            bf16x8 af[4], bfr[4];
#pragma unroll
            for (int i = 0; i < 4; ++i) {
                int row = wm * 64 + i * 16 + (lane & 15);
                af[i] = *(const bf16x8*)(AsB + row * 128 + ((kc ^ (row & 7)) << 4));
            }
#pragma unroll
            for (int j = 0; j < 4; ++j) {
                int col = wn * 64 + j * 16 + (lane & 15);
                bfr[j] = *(const bf16x8*)(BsB + col * 128 + ((kc ^ (col & 7)) << 4));
            }
#pragma unroll
            for (int i = 0; i < 4; ++i)
#pragma unroll
                for (int j = 0; j < 4; ++j)
                    acc[i][j] = __builtin_amdgcn_mfma_f32_16x16x32_bf16(af[i], bfr[j], acc[i][j], 0, 0, 0);
        }
        __syncthreads();
    }

    if (n0 < 256) {
#pragma unroll
        for (int i = 0; i < 4; ++i)
#pragma unroll
            for (int j = 0; j < 4; ++j)
#pragma unroll
                for (int q = 0; q < 4; ++q) {
                    int row = m0 + wm * 64 + i * 16 + (lane >> 4) * 4 + q;
                    int col = n0 + wn * 64 + j * 16 + (lane & 15);
                    node_proj_s[(size_t)row * P_DIM + col] = (acc[i][j][q] + biasF[col]) * TANH_C;
                }
    } else {
#pragma unroll
        for (int i = 0; i < 4; ++i)
#pragma unroll
            for (int j = 0; j < 4; ++j)
#pragma unroll
                for (int q = 0; q < 4; ++q) {
                    int row = m0 + wm * 64 + i * 16 + (lane >> 4) * 4 + q;
                    int col = n0 - 256 + wn * 64 + j * 16 + (lane & 15);
                    cat[(size_t)row * D_IMG + DD_OUT + col] = f2bf(acc[i][j][q] + biasN[col]);
                }
    }
}

// ================= fp32 -> bf16 convert =================
__global__ __launch_bounds__(256) void cvt_f32_bf16(
    const float* __restrict__ in, ushort* __restrict__ out, int n4)
{
    int i = blockIdx.x * 256 + threadIdx.x;
    if (i >= n4) return;
    float4 v = ((const float4*)in)[i];
    ushort4v o;
    o[0] = f2bf(v.x); o[1] = f2bf(v.y); o[2] = f2bf(v.z); o[3] = f2bf(v.w);
    ((ushort4v*)out)[i] = o;
}

// ================= W [K][N] fp32 -> WT [N][K] bf16 =================
__global__ __launch_bounds__(256) void transpose_cvt(
    const float* __restrict__ W, ushort* __restrict__ WT, int K, int N)
{
    __shared__ float t[64][65];
    const int n0 = blockIdx.x * 64, k0 = blockIdx.y * 64;
    const int tx = threadIdx.x & 15, ty = threadIdx.x >> 4;
#pragma unroll
    for (int r = 0; r < 4; ++r) {
        float4 v = *(const float4*)&W[(size_t)(k0 + ty * 4 + r) * N + n0 + tx * 4];
        t[ty * 4 + r][tx * 4 + 0] = v.x;
        t[ty * 4 + r][tx * 4 + 1] = v.y;
        t[ty * 4 + r][tx * 4 + 2] = v.z;
        t[ty * 4 + r][tx * 4 + 3] = v.w;
    }
    __syncthreads();
    const int nl = threadIdx.x >> 2, kq = (threadIdx.x & 3) * 16;
    ushort u[16] __attribute__((aligned(16)));
#pragma unroll
    for (int c = 0; c < 16; ++c) u[c] = f2bf(t[kq + c][nl]);
    ushort* d = &WT[(size_t)(n0 + nl) * K + k0 + kq];
    *(ushort8v*)d = *(ushort8v*)&u[0];
    *(ushort8v*)(d + 8) = *(ushort8v*)&u[8];
}

// ================= attention logits + softmax =================
// 2 waves/block, wave = node, lane = 4 channels. Per region: 1 fma + exp + add +
// rcp + fma per channel, partial -> LDS. End: lanes 0..35 row-sum + softmax.
// Uses logit' = -2 * sum(wa*rcp(e^{2x}+1)); the sum(wa) term cancels in softmax.
// node_proj_s is pre-scaled by 2*log2(e) in the producing GEMM epilogue.
__global__ __launch_bounds__(128, 4) void att_kernel(
    const float* __restrict__ node_proj_s, const float* __restrict__ img_proj,
    const int* __restrict__ batch_ids, const float* __restrict__ Wa,
    float* __restrict__ att)
{
    __shared__ float red[2][R_REG][68];
    const int wv = threadIdx.x >> 6;
    const int n = blockIdx.x * 2 + wv;
    const int lane = threadIdx.x & 63;
    const int b = batch_ids[n];

    const float4 nps = *(const float4*)(node_proj_s + (size_t)n * P_DIM + 4 * lane);
    const float4 wa = *(const float4*)(Wa + 4 * lane);
    const float* ip0 = img_proj + (size_t)b * R_REG * P_DIM + 4 * lane;

#pragma unroll
    for (int r = 0; r < R_REG; ++r) {
        float4 ip = *(const float4*)(ip0 + (size_t)r * P_DIM);
        float t0 = fexp2(fmaf(ip.x, TANH_C, nps.x));
        float t1 = fexp2(fmaf(ip.y, TANH_C, nps.y));
        float t2 = fexp2(fmaf(ip.z, TANH_C, nps.z));
        float t3 = fexp2(fmaf(ip.w, TANH_C, nps.w));
        float p;
        p = wa.x * frcp(t0 + 1.f);
        p = fmaf(wa.y, frcp(t1 + 1.f), p);
        p = fmaf(wa.z, frcp(t2 + 1.f), p);
        p = fmaf(wa.w, frcp(t3 + 1.f), p);
        red[wv][r][lane] = p;
    }
    __syncthreads();

    float logit = -INFINITY;
    if (lane < R_REG) {
        const float* row = &red[wv][lane][0];
        float4 s4 = *(const float4*)row;
#pragma unroll
        for (int c = 4; c < 64; c += 4) {
            float4 v = *(const float4*)(row + c);
            s4.x += v.x; s4.y += v.y; s4.z += v.z; s4.w += v.w;
        }
        logit = -2.f * ((s4.x + s4.y) + (s4.z + s4.w));
    }
    float m = logit;
#pragma unroll
    for (int off = 32; off; off >>= 1) m = fmaxf(m, __shfl_xor(m, off));
    float e = (lane < R_REG) ? __expf(logit - m) : 0.f;
    float s = e;
#pragma unroll
    for (int off = 32; off; off >>= 1) s += __shfl_xor(s, off);
    if (lane < R_REG) att[(size_t)n * R_REG + lane] = e / s;
}

// ================= batched attended image feature =================
#define IA_SLICES 8
__global__ __launch_bounds__(256) void img_att_batched(
    const float* __restrict__ att, const float* __restrict__ img_feats,
    const int* __restrict__ boffs, const int* __restrict__ nlist,
    ushort* __restrict__ img_bf)
{
    const int b     = blockIdx.x & 63;
    const int chunk = (blockIdx.x >> 6) & 1;
    const int slice = blockIdx.x >> 7;
    const int t = threadIdx.x;
    const int c0 = chunk * 512 + 2 * t;

    const int ns = boffs[b], ne = boffs[b + 1];
    const int cnt = ne - ns;
    const int per = (cnt + IA_SLICES - 1) / IA_SLICES;
    const int i0 = ns + slice * per;
    const int i1 = min(i0 + per, ne);
    if (i0 >= i1) return;

    float2 col[R_REG];
    const float* base = img_feats + (size_t)b * R_REG * D_IMG + c0;
#pragma unroll
    for (int r = 0; r < R_REG; ++r)
        col[r] = *(const float2*)(base + (size_t)r * D_IMG);

    __shared__ float att_s[8][R_REG];
    for (int i = i0; i < i1; i += 8) {
        int g = min(8, i1 - i);
        __syncthreads();
        for (int idx = t; idx < g * R_REG; idx += 256) {
            int j = idx / R_REG, r = idx - j * R_REG;
            att_s[j][r] = att[(size_t)nlist[i + j] * R_REG + r];
        }
        __syncthreads();
        for (int j = 0; j < g; ++j) {
            float4 av[9];
#pragma unroll
            for (int q = 0; q < 9; ++q) av[q] = *(const float4*)&att_s[j][q * 4];
            float ax = 0.f, ay = 0.f;
#pragma unroll
            for (int r = 0; r < R_REG; ++r) {
                float a = (r & 2) ? ((r & 1) ? av[r >> 2].w : av[r >> 2].z)
                                  : ((r & 1) ? av[r >> 2].y : av[r >> 2].x);
                ax += a * col[r].x;
                ay += a * col[r].y;
            }
            ushort2 o; o.x = f2bf(ax); o.y = f2bf(ay);
            *(ushort2*)&img_bf[(size_t)nlist[i + j] * D_IMG + c0] = o;
        }
    }
}

// ================= counting sorts =================
__global__ __launch_bounds__(256) void count_deg(const int* __restrict__ dst, int* __restrict__ deg) {
    int i = blockIdx.x * 256 + threadIdx.x;
    if (i < E_EDGES) atomicAdd(&deg[dst[i]], 1);
}

__global__ __launch_bounds__(256) void scan_deg(const int* __restrict__ deg, int* __restrict__ off) {
    __shared__ int s[257];
    const int t = threadIdx.x;
    const int base = t * 48;
    int sum = 0;
    for (int j = 0; j < 48; ++j) sum += deg[base + j];
    s[t] = sum;
    __syncthreads();
    if (t == 0) {
        int acc = 0;
        for (int i = 0; i < 256; ++i) { int v = s[i]; s[i] = acc; acc += v; }
        s[256] = acc;
    }
    __syncthreads();
    int run = s[t];
    for (int j = 0; j < 48; ++j) { off[base + j] = run; run += deg[base + j]; }
    if (t == 255) off[N_NODES] = s[256];
}

__global__ __launch_bounds__(256) void scatter_edges(
    const int* __restrict__ src, const int* __restrict__ dst,
    const int* __restrict__ off, int* __restrict__ cur, int* __restrict__ ssrc)
{
    int i = blockIdx.x * 256 + threadIdx.x;
    if (i < E_EDGES) {
        int d = dst[i];
        int p = off[d] + atomicAdd(&cur[d], 1);
        ssrc[p] = src[i];
    }
}

__global__ __launch_bounds__(256) void count_batch(const int* __restrict__ bid, int* __restrict__ bcnt) {
    int i = blockIdx.x * 256 + threadIdx.x;
    if (i < N_NODES) atomicAdd(&bcnt[bid[i]], 1);
}

__global__ __launch_bounds__(64) void scan_batch(const int* __restrict__ bcnt, int* __restrict__ boffs) {
    if (threadIdx.x == 0) {
        int acc = 0;
        for (int i = 0; i < B_EX; ++i) { boffs[i] = acc; acc += bcnt[i]; }
        boffs[B_EX] = acc;
    }
}

__global__ __launch_bounds__(256) void scatter_batch(
    const int* __restrict__ bid, const int* __restrict__ boffs,
    int* __restrict__ bcur, int* __restrict__ nlist)
{
    int i = blockIdx.x * 256 + threadIdx.x;
    if (i < N_NODES) {
        int b = bid[i];
        int p = boffs[b] + atomicAdd(&bcur[b], 1);
        nlist[p] = i;
    }
}

// ================= CSR gather: neigh[n] = sum over in-edges of h1[src] =================
__global__ __launch_bounds__(256) void gather_neigh(
    const int* __restrict__ off, const int* __restrict__ ssrc,
    const ushort* __restrict__ h1b /* cat+512, ld 1024 */, float* __restrict__ neigh)
{
    const int n = blockIdx.x, t = threadIdx.x;
    const int e0 = off[n], e1 = off[n + 1];
    float a0 = 0.f, a1 = 0.f;
    for (int e = e0; e < e1; ++e) {
        const uint32_t* row = (const uint32_t*)(h1b + (size_t)ssrc[e] * 1024);
        uint32_t v = row[t];
        a0 += bf2f((ushort)(v & 0xffffu));
        a1 += bf2f((ushort)(v >> 16));
    }
    float2 o; o.x = a0; o.y = a1;
    *(float2*)&neigh[(size_t)n * DD_OUT + 2 * t] = o;
}

extern "C" void kernel_launch(void* const* d_in, const int* in_sizes, int n_in,
                              void* d_out, int out_size, void* d_ws, size_t ws_size,
                              hipStream_t stream) {
    const float* h         = (const float*)d_in[0];
    const float* img_feats = (const float*)d_in[1];
    const int*   batch_ids = (const int*)d_in[2];
    const int*   src       = (const int*)d_in[3];
    const int*   dst       = (const int*)d_in[4];
    const float* Wf  = (const float*)d_in[5];
    const float* bf  = (const float*)d_in[6];
    const float* Wi  = (const float*)d_in[7];
    const float* bi  = (const float*)d_in[8];
    const float* Wa  = (const float*)d_in[9];
    const float* Wn  = (const float*)d_in[11];
    const float* bn  = (const float*)d_in[12];
    const float* Wim = (const float*)d_in[13];
    const float* bim = (const float*)d_in[14];
    const float* Wap = (const float*)d_in[15];
    const float* bap = (const float*)d_in[16];
    float* out = (float*)d_out;
    float* ws  = (float*)d_ws;

    // ---- workspace layout (offsets in 4-byte units) ----
    ushort* h_bf    = (ushort*)(ws + 0);         // [12288][512] bf16
    ushort* img_bf  = (ushort*)(ws + 3145728);   // [12288][1024] bf16
    float*  node_proj = ws + 9437184;            // [12288][256] f32 (pre-scaled)
    float*  img_proj  = ws + 12582912;           // [2304][256]  f32
    ushort* imgf_bf   = (ushort*)(ws + 13172736);// [2304][1024] bf16
    float*  att       = ws + 14352384;           // [12288][36]  f32
    float*  neigh     = ws + 9437184;            // [12288][512] f32 (overlays, after att+img_att)
    ushort* cat       = (ushort*)(ws + 15728640);// [12288][1024] bf16: cols 0-511 msg, 512-1023 h1
    ushort* WfnT = (ushort*)(ws + 22020096);     // [768][512]: rows 0-255 Wf^T, 256-767 Wn^T
    ushort* WiT  = (ushort*)(ws + 22216704);     // [256][1024]
    ushort* WimT = (ushort*)(ws + 22347776);     // [512][1024]
    ushort* WapT = (ushort*)(ws + 22609920);     // [512][1024]
    int* deg  = (int*)(ws + 22872064);           // [12288]
    int* cur  = deg + N_NODES;                   // [12288]
    int* offs = cur + N_NODES;                   // [12289]
    int* ssrc = offs + N_NODES + 1;              // [196608]
    int* bcnt = ssrc + E_EDGES;                  // [64]
    int* bcur = bcnt + B_EX;                     // [64]
    int* boffs = bcur + B_EX;                    // [65]
    int* nlist = boffs + B_EX + 1;               // [12288]

    dim3 blk(256);

    // ---- converts & weight transposes ----
    cvt_f32_bf16<<<dim3((N_NODES * DD_IN / 4 + 255) / 256), blk, 0, stream>>>(h, h_bf, N_NODES * DD_IN / 4);
    cvt_f32_bf16<<<dim3((B_EX * R_REG * D_IMG / 4 + 255) / 256), blk, 0, stream>>>(img_feats, imgf_bf, B_EX * R_REG * D_IMG / 4);
    transpose_cvt<<<dim3(P_DIM / 64, DD_IN / 64), blk, 0, stream>>>(Wf, WfnT, DD_IN, P_DIM);
    transpose_cvt<<<dim3(DD_OUT / 64, DD_IN / 64), blk, 0, stream>>>(Wn, WfnT + (size_t)P_DIM * DD_IN, DD_IN, DD_OUT);
    transpose_cvt<<<dim3(P_DIM / 64, D_IMG / 64), blk, 0, stream>>>(Wi, WiT, D_IMG, P_DIM);
    transpose_cvt<<<dim3(DD_OUT / 64, D_IMG / 64), blk, 0, stream>>>(Wim, WimT, D_IMG, DD_OUT);
    transpose_cvt<<<dim3(DD_OUT / 64, (2 * DD_OUT) / 64), blk, 0, stream>>>(Wap, WapT, 2 * DD_OUT, DD_OUT);

    // ---- CSR build (edges by dst) + node sort by batch ----
    hipMemsetAsync(deg, 0, 2 * N_NODES * sizeof(int), stream);
    hipMemsetAsync(bcnt, 0, 2 * B_EX * sizeof(int), stream);
    count_deg<<<dim3(E_EDGES / 256), blk, 0, stream>>>(dst, deg);
    scan_deg<<<dim3(1), blk, 0, stream>>>(deg, offs);
    scatter_edges<<<dim3(E_EDGES / 256), blk, 0, stream>>>(src, dst, offs, cur, ssrc);
    count_batch<<<dim3(N_NODES / 256), blk, 0, stream>>>(batch_ids, bcnt);
    scan_batch<<<dim3(1), dim3(64), 0, stream>>>(bcnt, boffs);
    scatter_batch<<<dim3(N_NODES / 256), blk, 0, stream>>>(batch_ids, boffs, bcur, nlist);

    // ---- fused: node_proj_s (scaled) + h1->cat cols 512..1023 ----
    gemm_fused_first<<<dim3((P_DIM + DD_OUT) / 128, N_NODES / 128), blk, 0, stream>>>(
        h_bf, WfnT, bf, bn, node_proj, cat);
    // ---- img_proj = img_feats @ Wi + bi ----
    gemm_bf16mfma<true, false, false, true, false><<<dim3(P_DIM / 128, (B_EX * R_REG) / 128), blk, 0, stream>>>(
        imgf_bf, WiT, bi, nullptr, img_proj, nullptr, B_EX * R_REG, P_DIM, D_IMG, 0, 0);
    // ---- attention ----
    att_kernel<<<dim3(N_NODES / 2), dim3(128), 0, stream>>>(node_proj, img_proj, batch_ids, Wa, att);
    img_att_batched<<<dim3(B_EX * 2 * IA_SLICES), blk, 0, stream>>>(att, img_feats, boffs, nlist, img_bf);
    // ---- neigh = segment_sum(h1[src], dst) via CSR ----
    gather_neigh<<<dim3(N_NODES), blk, 0, stream>>>(offs, ssrc, cat + DD_OUT, neigh);
    // ---- msg = neigh + img @ Wim + bim -> cat cols 0..511 (bf16) ----
    gemm_bf16mfma<true, true, false, false, true><<<dim3(DD_OUT / 128, N_NODES / 128), blk, 0, stream>>>(
        img_bf, WimT, bim, neigh, nullptr, cat, N_NODES, DD_OUT, D_IMG, D_IMG, 0);
    // ---- out = relu(cat @ Wap + bap) ----
    gemm_bf16mfma<true, false, true, true, false><<<dim3(DD_OUT / 128, N_NODES / 128), blk, 0, stream>>>(
        cat, WapT, bap, nullptr, out, nullptr, N_NODES, DD_OUT, 2 * DD_OUT, 0, 0);
}